// Round 3
// baseline (368.062 us; speedup 1.0000x reference)
//
#include <hip/hip_runtime.h>
#include <cstdint>
#include <cstddef>

typedef unsigned short u16;
typedef __bf16 bf16x8 __attribute__((ext_vector_type(8)));
typedef float f32x4 __attribute__((ext_vector_type(4)));

#define KOFF 27
#define EPSBN 1e-5f

__device__ inline u16 f2bf(float f) {
  unsigned int u = __float_as_uint(f);
  unsigned int r = (u + 0x7FFFu + ((u >> 16) & 1u)) >> 16;  // RNE
  return (u16)r;
}
__device__ inline float bf2f(u16 h) {
  return __uint_as_float(((unsigned int)h) << 16);
}

// ---------------- prep kernels ----------------

// cast feats -> bf16; block 0 also zeroes the 256-float stats accumulators
__global__ void k_prep_feats(const float* __restrict__ in, u16* __restrict__ out,
                             float* __restrict__ stats, int n4) {
  if (blockIdx.x == 0) stats[threadIdx.x] = 0.f;
  int i = blockIdx.x * 256 + threadIdx.x;
  if (i >= n4) return;
  const float4 v = reinterpret_cast<const float4*>(in)[i];
  ushort4 o;
  o.x = f2bf(v.x); o.y = f2bf(v.y); o.z = f2bf(v.z); o.w = f2bf(v.w);
  reinterpret_cast<ushort4*>(out)[i] = o;
}

// Pack W[k][j][c] (27x64x64 f32) into per-lane MFMA B-fragment order (bf16):
// Wp[ k*4096 + ks*2048 + ct*512 + lane*8 + e ] = W[k][ ks*32 + (lane>>4)*8 + e ][ ct*16 + (lane&15) ]
__global__ void k_prep_w(const float* __restrict__ W, u16* __restrict__ Wp) {
  int tid = blockIdx.x * 256 + threadIdx.x;
  if (tid >= KOFF * 4096) return;
  int k = tid >> 12;
  int rem = tid & 4095;
  int slot = rem >> 3;
  int e = rem & 7;
  int ks = slot >> 8;
  int ct = (slot >> 6) & 3;
  int lane = slot & 63;
  int j = ks * 32 + ((lane >> 4) << 3) + e;
  int c = ct * 16 + (lane & 15);
  Wp[tid] = f2bf(W[(k * 64 + j) * 64 + c]);
}

// Transpose nbr [N,27] -> nbrT [27,N] via LDS tiles (coalesced both sides)
__global__ void k_prep_nbrT(const int* __restrict__ nbr, int* __restrict__ nbrT, int N) {
  __shared__ int L[64 * KOFF];
  const int t = threadIdx.x;
  const int v0 = blockIdx.x * 64;
  const int nv = min(64, N - v0);
  const int cnt = nv * KOFF;
  for (int i = t; i < cnt; i += 256) L[i] = nbr[(size_t)v0 * KOFF + i];
  __syncthreads();
  for (int i = t; i < KOFF * 64; i += 256) {
    int k = i >> 6, j = i & 63;
    if (j < nv) nbrT[(size_t)k * N + v0 + j] = L[j * KOFF + k];
  }
}

// ---------------- conv: software-pipelined, register double-buffered ----------------
// Block 256 = 4 waves; wave owns 64 voxels x 64 out-channels (4x4 16x16x32 frags).
// Iteration k: issue A(k+1) gathers (using nid loaded last iter), nid(k+2), B(k+1);
// then MFMA on k's registered buffers. No barriers in the main loop.

__device__ __forceinline__ void conv_step(
    const u16* __restrict__ F, const u16* __restrict__ bp,
    const int* __restrict__ nbrT, int N, int vbase, const bool (&vok)[4],
    int kk, int chb,
    bf16x8 (&c0)[4], bf16x8 (&c1)[4], bf16x8 (&cb)[2][4], bool (&cball)[4],
    bf16x8 (&n0)[4], bf16x8 (&n1)[4], bf16x8 (&nb)[2][4], bool (&nball)[4],
    int (&nid)[4], f32x4 (&acc)[4][4]) {
  const int kn = kk + 1;
  if (kn < KOFF) {
    // A(k+1) gathers into the 'next' buffers (ids already in registers)
#pragma unroll
    for (int m = 0; m < 4; ++m) {
      const int id = nid[m];
      nball[m] = __any(id >= 0);
      n0[m] = (bf16x8){};
      n1[m] = (bf16x8){};
      if (id >= 0) {
        const char* fr = (const char*)F + ((size_t)(unsigned)id << 7) + chb;
        n0[m] = *reinterpret_cast<const bf16x8*>(fr);
        n1[m] = *reinterpret_cast<const bf16x8*>(fr + 64);
      }
    }
    // nid(k+2)
    if (kn + 1 < KOFF) {
      const int* nk = nbrT + (size_t)(kn + 1) * N + vbase;
#pragma unroll
      for (int m = 0; m < 4; ++m) nid[m] = vok[m] ? nk[m << 4] : -1;
    }
    // B(k+1) (pre-packed fragment order; L1/L2-resident)
    const u16* bk = bp + ((size_t)kn << 12);
#pragma unroll
    for (int ks = 0; ks < 2; ++ks)
#pragma unroll
      for (int c = 0; c < 4; ++c)
        nb[ks][c] = *reinterpret_cast<const bf16x8*>(bk + (ks << 11) + (c << 9));
  }
  // MFMA cluster on current buffers (loads above stay in flight)
  __builtin_amdgcn_s_setprio(1);
#pragma unroll
  for (int m = 0; m < 4; ++m) {
    if (cball[m]) {
#pragma unroll
      for (int c = 0; c < 4; ++c)
        acc[m][c] = __builtin_amdgcn_mfma_f32_16x16x32_bf16(c0[m], cb[0][c], acc[m][c], 0, 0, 0);
#pragma unroll
      for (int c = 0; c < 4; ++c)
        acc[m][c] = __builtin_amdgcn_mfma_f32_16x16x32_bf16(c1[m], cb[1][c], acc[m][c], 0, 0, 0);
    }
  }
  __builtin_amdgcn_s_setprio(0);
}

__launch_bounds__(256, 2)
__global__ void k_conv(const u16* __restrict__ F, const u16* __restrict__ Wp,
                       const int* __restrict__ nbrT, u16* __restrict__ rawout,
                       float* __restrict__ stats, int N) {
  const int t = threadIdx.x;
  const int w = t >> 6;
  const int lane = t & 63;

  // bijective XCD-aware block swizzle (m204 form)
  const int nwg = gridDim.x, bid = blockIdx.x;
  const int q = nwg >> 3, r = nwg & 7;
  const int xcd = bid & 7, o = bid >> 3;
  const int wg = (xcd < r ? xcd * (q + 1) : r * (q + 1) + (xcd - r) * q) + o;

  const int vbase = wg * 256 + (w << 6) + (lane & 15);
  const int chb = (lane >> 4) << 4;  // A-frag channel byte offset

  f32x4 acc[4][4];
#pragma unroll
  for (int m = 0; m < 4; ++m)
#pragma unroll
    for (int c = 0; c < 4; ++c) acc[m][c] = (f32x4){0.f, 0.f, 0.f, 0.f};

  bool vok[4];
  int nid[4];
#pragma unroll
  for (int m = 0; m < 4; ++m) {
    const int v = vbase + (m << 4);
    vok[m] = v < N;
    nid[m] = vok[m] ? nbrT[v] : -1;  // ids for k=0
  }

  bf16x8 a0A[4], a1A[4], bA[2][4];
  bf16x8 a0B[4], a1B[4], bB[2][4];
  bool ballA[4], ballB[4];

  // prologue: k=0 data into the A set, nid <- k=1
#pragma unroll
  for (int m = 0; m < 4; ++m) {
    const int id = nid[m];
    ballA[m] = __any(id >= 0);
    a0A[m] = (bf16x8){};
    a1A[m] = (bf16x8){};
    if (id >= 0) {
      const char* fr = (const char*)F + ((size_t)(unsigned)id << 7) + chb;
      a0A[m] = *reinterpret_cast<const bf16x8*>(fr);
      a1A[m] = *reinterpret_cast<const bf16x8*>(fr + 64);
    }
  }
  {
    const int* nk = nbrT + (size_t)N + vbase;
#pragma unroll
    for (int m = 0; m < 4; ++m) nid[m] = vok[m] ? nk[m << 4] : -1;  // ids for k=1
  }
  const u16* bp = Wp + (lane << 3);
#pragma unroll
  for (int ks = 0; ks < 2; ++ks)
#pragma unroll
    for (int c = 0; c < 4; ++c)
      bA[ks][c] = *reinterpret_cast<const bf16x8*>(bp + (ks << 11) + (c << 9));

  for (int kb = 0; kb < 13; ++kb) {
    conv_step(F, bp, nbrT, N, vbase, vok, 2 * kb, chb,
              a0A, a1A, bA, ballA, a0B, a1B, bB, ballB, nid, acc);
    conv_step(F, bp, nbrT, N, vbase, vok, 2 * kb + 1, chb,
              a0B, a1B, bB, ballB, a0A, a1A, bA, ballA, nid, acc);
  }
  conv_step(F, bp, nbrT, N, vbase, vok, 26, chb,
            a0A, a1A, bA, ballA, a0B, a1B, bB, ballB, nid, acc);

  // ---- store raw bf16 + fused BN-stat partial reduction ----
  const int row0 = wg * 256 + (w << 6) + ((lane >> 4) << 2);
#pragma unroll
  for (int m = 0; m < 4; ++m) {
#pragma unroll
    for (int c = 0; c < 4; ++c) {
      const int col = (c << 4) + (lane & 15);
#pragma unroll
      for (int e = 0; e < 4; ++e) {
        const int v = row0 + (m << 4) + e;
        if (v < N) rawout[((size_t)v << 6) + col] = f2bf(acc[m][c][e]);
      }
    }
  }

  __shared__ float sred[4][128];
#pragma unroll
  for (int c = 0; c < 4; ++c) {
    float s = 0.f, qq = 0.f;
#pragma unroll
    for (int m = 0; m < 4; ++m)
#pragma unroll
      for (int e = 0; e < 4; ++e) {
        const float x = acc[m][c][e];  // OOB rows stay exact 0
        s += x;
        qq += x * x;
      }
    s += __shfl_xor(s, 16, 64);
    s += __shfl_xor(s, 32, 64);
    qq += __shfl_xor(qq, 16, 64);
    qq += __shfl_xor(qq, 32, 64);
    if (lane < 16) {
      sred[w][(c << 4) + lane] = s;
      sred[w][64 + (c << 4) + lane] = qq;
    }
  }
  __syncthreads();
  if (t < 128) {
    const float tot = sred[0][t] + sred[1][t] + sred[2][t] + sred[3][t];
    atomicAdd(&stats[t], tot);
  }
}

// ---------------- BN finalize / apply ----------------

__global__ void k_final(const float* __restrict__ stats, const float* __restrict__ gamma,
                        const float* __restrict__ beta, float* __restrict__ sb, int N) {
  const int c = threadIdx.x;  // 64
  const float inv = 1.0f / (float)N;
  const float mu = stats[c] * inv;
  const float var = stats[64 + c] * inv - mu * mu;
  const float sc = gamma[c] * rsqrtf(var + EPSBN);
  sb[c] = sc;
  sb[64 + c] = beta[c] - mu * sc;
}

// x_net = relu(raw*sc+bi) -> bf16   (raw is bf16, 8 elems/thread)
__global__ void k_apply1(const u16* __restrict__ raw, const float* __restrict__ sb,
                         u16* __restrict__ xb, int n8) {
  int i = blockIdx.x * 256 + threadIdx.x;
  if (i >= n8) return;
  const int cg = (i & 7) << 1;
  const uint4 rv = reinterpret_cast<const uint4*>(raw)[i];
  const float4 s0 = reinterpret_cast<const float4*>(sb)[cg];
  const float4 s1 = reinterpret_cast<const float4*>(sb)[cg + 1];
  const float4 b0 = reinterpret_cast<const float4*>(sb + 64)[cg];
  const float4 b1 = reinterpret_cast<const float4*>(sb + 64)[cg + 1];
  uint4 ov;
  {
    float y0 = fmaxf(0.f, bf2f((u16)(rv.x & 0xffff)) * s0.x + b0.x);
    float y1 = fmaxf(0.f, bf2f((u16)(rv.x >> 16)) * s0.y + b0.y);
    float y2 = fmaxf(0.f, bf2f((u16)(rv.y & 0xffff)) * s0.z + b0.z);
    float y3 = fmaxf(0.f, bf2f((u16)(rv.y >> 16)) * s0.w + b0.w);
    ov.x = (unsigned)f2bf(y0) | ((unsigned)f2bf(y1) << 16);
    ov.y = (unsigned)f2bf(y2) | ((unsigned)f2bf(y3) << 16);
  }
  {
    float y0 = fmaxf(0.f, bf2f((u16)(rv.z & 0xffff)) * s1.x + b1.x);
    float y1 = fmaxf(0.f, bf2f((u16)(rv.z >> 16)) * s1.y + b1.y);
    float y2 = fmaxf(0.f, bf2f((u16)(rv.w & 0xffff)) * s1.z + b1.z);
    float y3 = fmaxf(0.f, bf2f((u16)(rv.w >> 16)) * s1.w + b1.w);
    ov.z = (unsigned)f2bf(y0) | ((unsigned)f2bf(y1) << 16);
    ov.w = (unsigned)f2bf(y2) | ((unsigned)f2bf(y3) << 16);
  }
  reinterpret_cast<uint4*>(xb)[i] = ov;
}

// out = x_net + relu(raw*sc+bi)   (raw,x_net bf16 -> out f32)
__global__ void k_apply2(const u16* __restrict__ raw, const float* __restrict__ sb,
                         const u16* __restrict__ xb, float* __restrict__ out, int n8) {
  int i = blockIdx.x * 256 + threadIdx.x;
  if (i >= n8) return;
  const int cg = (i & 7) << 1;
  const uint4 rv = reinterpret_cast<const uint4*>(raw)[i];
  const uint4 xv = reinterpret_cast<const uint4*>(xb)[i];
  const float4 s0 = reinterpret_cast<const float4*>(sb)[cg];
  const float4 s1 = reinterpret_cast<const float4*>(sb)[cg + 1];
  const float4 b0 = reinterpret_cast<const float4*>(sb + 64)[cg];
  const float4 b1 = reinterpret_cast<const float4*>(sb + 64)[cg + 1];
  float4 o0, o1;
  o0.x = bf2f((u16)(xv.x & 0xffff)) + fmaxf(0.f, bf2f((u16)(rv.x & 0xffff)) * s0.x + b0.x);
  o0.y = bf2f((u16)(xv.x >> 16)) + fmaxf(0.f, bf2f((u16)(rv.x >> 16)) * s0.y + b0.y);
  o0.z = bf2f((u16)(xv.y & 0xffff)) + fmaxf(0.f, bf2f((u16)(rv.y & 0xffff)) * s0.z + b0.z);
  o0.w = bf2f((u16)(xv.y >> 16)) + fmaxf(0.f, bf2f((u16)(rv.y >> 16)) * s0.w + b0.w);
  o1.x = bf2f((u16)(xv.z & 0xffff)) + fmaxf(0.f, bf2f((u16)(rv.z & 0xffff)) * s1.x + b1.x);
  o1.y = bf2f((u16)(xv.z >> 16)) + fmaxf(0.f, bf2f((u16)(rv.z >> 16)) * s1.y + b1.y);
  o1.z = bf2f((u16)(xv.w & 0xffff)) + fmaxf(0.f, bf2f((u16)(rv.w & 0xffff)) * s1.z + b1.z);
  o1.w = bf2f((u16)(xv.w >> 16)) + fmaxf(0.f, bf2f((u16)(rv.w >> 16)) * s1.w + b1.w);
  reinterpret_cast<float4*>(out)[2 * i] = o0;
  reinterpret_cast<float4*>(out)[2 * i + 1] = o1;
}

// ---------------- host ----------------

extern "C" void kernel_launch(void* const* d_in, const int* in_sizes, int n_in,
                              void* d_out, int out_size, void* d_ws, size_t ws_size,
                              hipStream_t stream) {
  const float* feats = (const float*)d_in[0];
  const float* W1 = (const float*)d_in[1];
  const float* g1 = (const float*)d_in[2];
  const float* b1 = (const float*)d_in[3];
  const float* W2 = (const float*)d_in[4];
  const float* g2 = (const float*)d_in[5];
  const float* b2 = (const float*)d_in[6];
  const int* nbr = (const int*)d_in[7];
  const int N = in_sizes[0] / 64;

  char* ws = (char*)d_ws;
  size_t off = 0;
  auto alloc = [&](size_t bytes) {
    void* p = ws + off;
    off = (off + bytes + 255) & ~(size_t)255;
    return p;
  };
  u16* featsb = (u16*)alloc((size_t)N * 64 * 2);
  u16* xnetb = (u16*)alloc((size_t)N * 64 * 2);
  u16* w1p = (u16*)alloc((size_t)KOFF * 4096 * 2);
  u16* w2p = (u16*)alloc((size_t)KOFF * 4096 * 2);
  float* stats = (float*)alloc(256 * 4);  // [s1 q1 s2 q2] x 64
  float* sb1 = (float*)alloc(128 * 4);
  float* sb2 = (float*)alloc(128 * 4);
  int* nbrT = (int*)alloc((size_t)KOFF * N * 4);

  u16* raw1 = (u16*)d_out;   // conv1 raw (bf16) scribbled into d_out
  u16* raw2 = featsb;        // conv2 raw reuses dead conv1-input buffer
  float* outf = (float*)d_out;

  const int n4 = N * 16;
  const int n8 = N * 8;
  const int gPrep = (n4 + 255) / 256;
  const int gApply = (n8 + 255) / 256;
  const int gW = (KOFF * 4096 + 255) / 256;
  const int gConv = (N + 255) / 256;

  k_prep_feats<<<gPrep, 256, 0, stream>>>(feats, featsb, stats, n4);
  k_prep_w<<<gW, 256, 0, stream>>>(W1, w1p);
  k_prep_w<<<gW, 256, 0, stream>>>(W2, w2p);
  k_prep_nbrT<<<(N + 63) / 64, 256, 0, stream>>>(nbr, nbrT, N);

  k_conv<<<gConv, 256, 0, stream>>>(featsb, w1p, nbrT, raw1, stats, N);
  k_final<<<1, 64, 0, stream>>>(stats, g1, b1, sb1, N);
  k_apply1<<<gApply, 256, 0, stream>>>(raw1, sb1, xnetb, n8);

  k_conv<<<gConv, 256, 0, stream>>>(xnetb, w2p, nbrT, raw2, stats + 128, N);
  k_final<<<1, 64, 0, stream>>>(stats + 128, g2, b2, sb2, N);
  k_apply2<<<gApply, 256, 0, stream>>>(raw2, sb2, xnetb, outf, n8);
}

// Round 4
// 324.802 us; speedup vs baseline: 1.1332x; 1.1332x over previous
//
#include <hip/hip_runtime.h>
#include <cstdint>
#include <cstddef>

typedef unsigned short u16;
typedef __bf16 bf16x8 __attribute__((ext_vector_type(8)));
typedef float f32x4 __attribute__((ext_vector_type(4)));

#define KOFF 27
#define EPSBN 1e-5f

__device__ inline u16 f2bf(float f) {
  unsigned int u = __float_as_uint(f);
  unsigned int r = (u + 0x7FFFu + ((u >> 16) & 1u)) >> 16;  // RNE
  return (u16)r;
}
__device__ inline float bf2f(u16 h) {
  return __uint_as_float(((unsigned int)h) << 16);
}

// ---------------- prep kernels ----------------

// cast feats -> bf16; block 0 also zeroes the 256-float stats accumulators
__global__ void k_prep_feats(const float* __restrict__ in, u16* __restrict__ out,
                             float* __restrict__ stats, int n4) {
  if (blockIdx.x == 0) stats[threadIdx.x] = 0.f;
  int i = blockIdx.x * 256 + threadIdx.x;
  if (i >= n4) return;
  const float4 v = reinterpret_cast<const float4*>(in)[i];
  ushort4 o;
  o.x = f2bf(v.x); o.y = f2bf(v.y); o.z = f2bf(v.z); o.w = f2bf(v.w);
  reinterpret_cast<ushort4*>(out)[i] = o;
}

// Pack W[k][j][c] (27x64x64 f32) into per-lane MFMA B-fragment order (bf16):
// Wp[ k*4096 + ks*2048 + ct*512 + lane*8 + e ] = W[k][ ks*32 + (lane>>4)*8 + e ][ ct*16 + (lane&15) ]
__global__ void k_prep_w(const float* __restrict__ W, u16* __restrict__ Wp) {
  int tid = blockIdx.x * 256 + threadIdx.x;
  if (tid >= KOFF * 4096) return;
  int k = tid >> 12;
  int rem = tid & 4095;
  int slot = rem >> 3;
  int e = rem & 7;
  int ks = slot >> 8;
  int ct = (slot >> 6) & 3;
  int lane = slot & 63;
  int j = ks * 32 + ((lane >> 4) << 3) + e;
  int c = ct * 16 + (lane & 15);
  Wp[tid] = f2bf(W[(k * 64 + j) * 64 + c]);
}

// Transpose nbr [N,27] -> nbrT [27,N] via LDS tiles (coalesced both sides)
__global__ void k_prep_nbrT(const int* __restrict__ nbr, int* __restrict__ nbrT, int N) {
  __shared__ int L[64 * KOFF];
  const int t = threadIdx.x;
  const int v0 = blockIdx.x * 64;
  const int nv = min(64, N - v0);
  const int cnt = nv * KOFF;
  for (int i = t; i < cnt; i += 256) L[i] = nbr[(size_t)v0 * KOFF + i];
  __syncthreads();
  for (int i = t; i < KOFF * 64; i += 256) {
    int k = i >> 6, j = i & 63;
    if (j < nv) nbrT[(size_t)k * N + v0 + j] = L[j * KOFF + k];
  }
}

// ---------------- conv kernel ----------------
// Block 256 = 4 waves; each wave owns 32 voxels x all 64 output channels
// (2x4 accumulator frags = 32 VGPR acc). Small per-wave footprint -> 4 waves/SIMD.
// A-fragments gathered straight from global (16B/lane, frag-layout-native);
// B-fragments read straight from global (pre-packed, L1-resident broadcast).
// Neighbor indices for k+1 prefetched. No barriers in main loop.
// Epilogue fuses BN batch-stat partial reduction (atomicAdd into stats[128]).
__launch_bounds__(256, 4)
__global__ void k_conv(const u16* __restrict__ F, const u16* __restrict__ Wp,
                       const int* __restrict__ nbrT, float* __restrict__ out,
                       float* __restrict__ stats, int N) {
  const int t = threadIdx.x;
  const int w = t >> 6;
  const int lane = t & 63;

  // bijective XCD-aware block swizzle (m204 form)
  const int nwg = gridDim.x, bid = blockIdx.x;
  const int q = nwg >> 3, r = nwg & 7;
  const int xcd = bid & 7, o = bid >> 3;
  const int wg = (xcd < r ? xcd * (q + 1) : r * (q + 1) + (xcd - r) * q) + o;

  const int vbase = wg * 128 + (w << 5) + (lane & 15);
  const int ch = (lane >> 4) << 3;  // A-frag channel offset (elements)

  f32x4 acc[2][4];
#pragma unroll
  for (int m = 0; m < 2; ++m)
#pragma unroll
    for (int c = 0; c < 4; ++c) acc[m][c] = (f32x4){0.f, 0.f, 0.f, 0.f};

  bool vok[2];
  int nid[2];
#pragma unroll
  for (int m = 0; m < 2; ++m) {
    const int v = vbase + (m << 4);
    vok[m] = v < N;
    nid[m] = vok[m] ? nbrT[v] : -1;
  }

  const u16* bp = Wp + (lane << 3);

#pragma unroll 3
  for (int k = 0; k < KOFF; ++k) {
    // B fragments for this k (broadcast across waves -> L1 hits)
    bf16x8 bfr[2][4];
#pragma unroll
    for (int ks = 0; ks < 2; ++ks)
#pragma unroll
      for (int c = 0; c < 4; ++c)
        bfr[ks][c] = *reinterpret_cast<const bf16x8*>(bp + ((size_t)k << 12) + (ks << 11) + (c << 9));

    // A fragments: direct register gather
    bf16x8 a0[2], a1[2];
#pragma unroll
    for (int m = 0; m < 2; ++m) {
      a0[m] = (bf16x8){};
      a1[m] = (bf16x8){};
      const int id = nid[m];
      if (id >= 0) {
        const u16* fr = F + ((size_t)(unsigned)id << 6) + ch;
        a0[m] = *reinterpret_cast<const bf16x8*>(fr);
        a1[m] = *reinterpret_cast<const bf16x8*>(fr + 32);
      }
    }

    // prefetch next k's indices (latency hidden under the MFMA block)
    if (k + 1 < KOFF) {
      const int* nk = nbrT + (size_t)(k + 1) * N;
#pragma unroll
      for (int m = 0; m < 2; ++m) {
        const int v = vbase + (m << 4);
        nid[m] = (v < N) ? nk[v] : -1;
      }
    }

#pragma unroll
    for (int m = 0; m < 2; ++m)
#pragma unroll
      for (int c = 0; c < 4; ++c)
        acc[m][c] = __builtin_amdgcn_mfma_f32_16x16x32_bf16(a0[m], bfr[0][c], acc[m][c], 0, 0, 0);
#pragma unroll
    for (int m = 0; m < 2; ++m)
#pragma unroll
      for (int c = 0; c < 4; ++c)
        acc[m][c] = __builtin_amdgcn_mfma_f32_16x16x32_bf16(a1[m], bfr[1][c], acc[m][c], 0, 0, 0);
  }

  // ---- store f32 + fused BN-stat partial reduction ----
  const int row0 = wg * 128 + (w << 5) + ((lane >> 4) << 2);
#pragma unroll
  for (int m = 0; m < 2; ++m) {
#pragma unroll
    for (int c = 0; c < 4; ++c) {
      const int col = (c << 4) + (lane & 15);
#pragma unroll
      for (int e = 0; e < 4; ++e) {
        const int v = row0 + (m << 4) + e;
        if (v < N) out[((size_t)v << 6) + col] = acc[m][c][e];
      }
    }
  }

  __shared__ float sred[4][128];
#pragma unroll
  for (int c = 0; c < 4; ++c) {
    float s = 0.f, qq = 0.f;
#pragma unroll
    for (int m = 0; m < 2; ++m)
#pragma unroll
      for (int e = 0; e < 4; ++e) {
        const float x = acc[m][c][e];  // OOB rows contribute exact 0
        s += x;
        qq += x * x;
      }
    s += __shfl_xor(s, 16, 64);
    s += __shfl_xor(s, 32, 64);
    qq += __shfl_xor(qq, 16, 64);
    qq += __shfl_xor(qq, 32, 64);
    if (lane < 16) {
      sred[w][(c << 4) + lane] = s;
      sred[w][64 + (c << 4) + lane] = qq;
    }
  }
  __syncthreads();
  if (t < 128) {
    const float tot = sred[0][t] + sred[1][t] + sred[2][t] + sred[3][t];
    atomicAdd(&stats[t], tot);
  }
}

// ---------------- BN finalize / apply ----------------

__global__ void k_final(const float* __restrict__ stats, const float* __restrict__ gamma,
                        const float* __restrict__ beta, float* __restrict__ sb, int N) {
  const int c = threadIdx.x;  // 64
  const float inv = 1.0f / (float)N;
  const float mu = stats[c] * inv;
  const float var = stats[64 + c] * inv - mu * mu;
  const float sc = gamma[c] * rsqrtf(var + EPSBN);
  sb[c] = sc;
  sb[64 + c] = beta[c] - mu * sc;
}

// y = relu(x*sc+bi) -> bf16 x_net
__global__ void k_apply1(const float* __restrict__ x, const float* __restrict__ sb,
                         u16* __restrict__ xb, int n4) {
  int i = blockIdx.x * 256 + threadIdx.x;
  if (i >= n4) return;
  const int cg = i & 15;
  float4 v = reinterpret_cast<const float4*>(x)[i];
  const float4 sc = reinterpret_cast<const float4*>(sb)[cg];
  const float4 bi = reinterpret_cast<const float4*>(sb)[16 + cg];
  float y0 = fmaxf(0.f, v.x * sc.x + bi.x);
  float y1 = fmaxf(0.f, v.y * sc.y + bi.y);
  float y2 = fmaxf(0.f, v.z * sc.z + bi.z);
  float y3 = fmaxf(0.f, v.w * sc.w + bi.w);
  ushort4 o;
  o.x = f2bf(y0); o.y = f2bf(y1); o.z = f2bf(y2); o.w = f2bf(y3);
  reinterpret_cast<ushort4*>(xb)[i] = o;
}

// out = x_net + relu(x*sc+bi)   (in-place on conv2 raw output)
__global__ void k_apply2(float* __restrict__ io, const float* __restrict__ sb,
                         const u16* __restrict__ xb, int n4) {
  int i = blockIdx.x * 256 + threadIdx.x;
  if (i >= n4) return;
  const int cg = i & 15;
  float4 v = reinterpret_cast<const float4*>(io)[i];
  const float4 sc = reinterpret_cast<const float4*>(sb)[cg];
  const float4 bi = reinterpret_cast<const float4*>(sb)[16 + cg];
  const ushort4 xn = reinterpret_cast<const ushort4*>(xb)[i];
  float4 o;
  o.x = bf2f(xn.x) + fmaxf(0.f, v.x * sc.x + bi.x);
  o.y = bf2f(xn.y) + fmaxf(0.f, v.y * sc.y + bi.y);
  o.z = bf2f(xn.z) + fmaxf(0.f, v.z * sc.z + bi.z);
  o.w = bf2f(xn.w) + fmaxf(0.f, v.w * sc.w + bi.w);
  reinterpret_cast<float4*>(io)[i] = o;
}

// ---------------- host ----------------

extern "C" void kernel_launch(void* const* d_in, const int* in_sizes, int n_in,
                              void* d_out, int out_size, void* d_ws, size_t ws_size,
                              hipStream_t stream) {
  const float* feats = (const float*)d_in[0];
  const float* W1 = (const float*)d_in[1];
  const float* g1 = (const float*)d_in[2];
  const float* b1 = (const float*)d_in[3];
  const float* W2 = (const float*)d_in[4];
  const float* g2 = (const float*)d_in[5];
  const float* b2 = (const float*)d_in[6];
  const int* nbr = (const int*)d_in[7];
  const int N = in_sizes[0] / 64;

  char* ws = (char*)d_ws;
  size_t off = 0;
  auto alloc = [&](size_t bytes) {
    void* p = ws + off;
    off = (off + bytes + 255) & ~(size_t)255;
    return p;
  };
  u16* featsb = (u16*)alloc((size_t)N * 64 * 2);
  u16* xnetb = (u16*)alloc((size_t)N * 64 * 2);
  u16* w1p = (u16*)alloc((size_t)KOFF * 4096 * 2);
  u16* w2p = (u16*)alloc((size_t)KOFF * 4096 * 2);
  float* stats = (float*)alloc(256 * 4);  // [s1 q1 s2 q2] x 64
  float* sb1 = (float*)alloc(128 * 4);
  float* sb2 = (float*)alloc(128 * 4);
  int* nbrT = (int*)alloc((size_t)KOFF * N * 4);
  float* outf = (float*)d_out;

  const int n4 = N * 16;
  const int gPrep = (n4 + 255) / 256;
  const int gW = (KOFF * 4096 + 255) / 256;
  const int gConv = (N + 127) / 128;

  k_prep_feats<<<gPrep, 256, 0, stream>>>(feats, featsb, stats, n4);
  k_prep_w<<<gW, 256, 0, stream>>>(W1, w1p);
  k_prep_w<<<gW, 256, 0, stream>>>(W2, w2p);
  k_prep_nbrT<<<(N + 63) / 64, 256, 0, stream>>>(nbr, nbrT, N);

  k_conv<<<gConv, 256, 0, stream>>>(featsb, w1p, nbrT, outf, stats, N);
  k_final<<<1, 64, 0, stream>>>(stats, g1, b1, sb1, N);
  k_apply1<<<gPrep, 256, 0, stream>>>(outf, sb1, xnetb, n4);

  k_conv<<<gConv, 256, 0, stream>>>(xnetb, w2p, nbrT, outf, stats + 128, N);
  k_final<<<1, 64, 0, stream>>>(stats + 128, g2, b2, sb2, N);
  k_apply2<<<gPrep, 256, 0, stream>>>(outf, sb2, xnetb, n4);
}